// Round 11
// baseline (4240.950 us; speedup 1.0000x reference)
//
#include <hip/hip_runtime.h>
#include <math.h>

#define T_ 128
#define B_ 64
#define E_ 300
#define H_ 2048

// ======== new-path geometry ========
// K layout: [0,300) x | [300,320) zero-pad | [320,2368) h   -> K1 = 2368 = 74 ksteps of 32
#define K1   2368
#define XKS  10      // x ksteps (320/32)
#define NKS  74      // total ksteps
#define APELEMS 19398656ull   // 8192 * 2368, per weight matrix (frag-major packed)
#define BXELEMS 5242880ull    // 128 t * 10 ks * 2 hl * 4 nf * 64 l * 8 j
#define BHPING  524288ull     // 64 ks * 16 nf * 64 l * 8 j   (shorts per ping)

typedef __attribute__((ext_vector_type(8))) short short8;
typedef __attribute__((ext_vector_type(4))) float float4v;

__device__ __forceinline__ unsigned f2bf(float f) {
    unsigned u = __float_as_uint(f);
    return (u + 0x7FFFu + ((u >> 16) & 1u)) >> 16;
}
__device__ __forceinline__ float bf2f(unsigned b) { return __uint_as_float(b << 16); }

__device__ __forceinline__ void gl_lds16(const void* g, void* l) {
    __builtin_amdgcn_global_load_lds(
        (const __attribute__((address_space(1))) unsigned int*)g,
        (__attribute__((address_space(3))) unsigned int*)l, 16, 0, 0);
}

__device__ __forceinline__ float sigm(float x) { return 1.f / (1.f + expf(-x)); }

// ================= new-path prologue =================

__global__ void init2(short* __restrict__ Bh, float* __restrict__ cb) {
    const int nB = 2 * (int)BHPING;     // shorts
    const int nC = 2 * 2048 * 64;       // floats
    int stride = gridDim.x * blockDim.x;
    int i = blockIdx.x * blockDim.x + threadIdx.x;
    for (int idx = i; idx < nB; idx += stride) Bh[idx] = 0;
    for (int idx = i; idx < nC; idx += stride) cb[idx] = 0.f;
}

// frag-major packed weights: [rb(64)][ks(74)][mf(8)][l(64)][j(8)]
// element = W[row = rb*128+mf*16+(l&15)][kr = ks*32+(l>>4)*8+j]
__global__ void pack_w(const float* __restrict__ Wih, const float* __restrict__ Whh,
                       short* __restrict__ Ahi, short* __restrict__ Alo) {
    long long idx = (long long)blockIdx.x * blockDim.x + threadIdx.x;
    if (idx >= (long long)APELEMS) return;
    int j  = (int)(idx & 7);
    int l  = (int)((idx >> 3) & 63);
    int mf = (int)((idx >> 9) & 7);
    int rest = (int)(idx >> 12);
    int ks = rest % 74;
    int rb = rest / 74;
    int row = rb * 128 + mf * 16 + (l & 15);
    int kr  = ks * 32 + (l >> 4) * 8 + j;
    float wv = 0.f;
    if (kr < 300)       wv = Wih[(size_t)row * 300 + kr];
    else if (kr >= 320) wv = Whh[(size_t)row * 2048 + (kr - 320)];
    unsigned hb = f2bf(wv);
    Ahi[idx] = (short)hb;
    Alo[idx] = (short)f2bf(wv - bf2f(hb));
}

// packed x: [t(128)][ks(10)][hl(2)][nf4(4)][l(64)][j(8)]
// col b = nf4*16+(l&15); kr = ks*32+(l>>4)*8+j
__global__ void pack_x(const int* __restrict__ tokens, const float* __restrict__ embed,
                       short* __restrict__ Bx) {
    long long idx = (long long)blockIdx.x * blockDim.x + threadIdx.x;
    if (idx >= (long long)BXELEMS) return;
    int j   = (int)(idx & 7);
    int l   = (int)((idx >> 3) & 63);
    int nf4 = (int)((idx >> 9) & 3);
    int hl  = (int)((idx >> 11) & 1);
    int rest = (int)(idx >> 12);
    int ks = rest % 10;
    int tt = rest / 10;
    int b  = nf4 * 16 + (l & 15);
    int kr = ks * 32 + (l >> 4) * 8 + j;
    float v = 0.f;
    if (kr < 300) {
        int tok = tokens[tt * 64 + b];
        v = embed[(size_t)tok * 300 + kr];
    }
    unsigned hb = f2bf(v);
    Bx[idx] = hl ? (short)f2bf(v - bf2f(hb)) : (short)hb;
}

// ================= new-path per-step GEMM =================
// 512 HOMOGENEOUS blocks = mb(64) x s(8); 256 threads (4 waves); 2 blocks/CU.
// Block M-tile 128 rows, k-split 9-10 ksteps. Two passes into the SAME
// accumulator (full 3-term sum): pass-hi Ahi x [vhi|vlo] merged, pass-lo
// Alo x vhi. PASS-ORDER STAGGER (round-11): blocks with (bb&1)^((bb>>8)&1)
// run lo-pass first so co-resident block pairs are in DIFFERENT passes --
// one block's MFMA bursts overlap the other's staging (forced m114 overlap).
// Scalarized staging addresses; 3-buffer counted-vmcnt pipeline, distance 2
// (vmcnt(6) hi / vmcnt(4) lo, never drained in-loop); tail over-fetch lands in
// adjacent ws buffers (valid, never consumed). vmcnt(0) drain between passes.
template<int HI>
__device__ __forceinline__ void pass10(
    const short* __restrict__ ApB,   // Ap + mb*74*4096
    const short* __restrict__ Bx,
    const short* __restrict__ BhP,   // Bh + ping*BHPING
    short* lds, float4v (&acc)[4][4],
    int ks0, int nks, int t, int tid, int wm, int wn, int l, int boff)
{
    auto stage = [&](int ks, int buf) {
        short* As = lds + buf * 12288;
        short* Bs = As + 4096;
        const short* aB = ApB + (size_t)ks * 4096;
        gl_lds16(aB + tid * 8, As + tid * 8);
        gl_lds16(aB + 2048 + tid * 8, As + 2048 + tid * 8);
        constexpr int NBL = HI ? 4 : 2;
#pragma unroll
        for (int q = 0; q < NBL; ++q) {
            const int dsel = HI ? (q >> 1) : q;   // compile-time per unrolled q
            const int hl   = HI ? (q & 1) : 0;
            const short* base;
            if (ks < XKS) {
                const int xt = dsel ? (127 - t) : t;
                base = Bx + (size_t)(((xt * 10 + ks) * 2 + hl) * 4) * 512;
            } else {
                base = BhP + (size_t)((ks - 10) * 16 + (dsel * 2 + hl) * 4) * 512;
            }
            gl_lds16(base + boff, Bs + q * 2048 + tid * 8);
        }
    };

    stage(ks0, 0);
    stage(ks0 + 1, 1);
    if constexpr (HI) { asm volatile("s_waitcnt vmcnt(6)" ::: "memory"); }
    else              { asm volatile("s_waitcnt vmcnt(4)" ::: "memory"); }
    __builtin_amdgcn_s_barrier();
    __builtin_amdgcn_sched_barrier(0);

    for (int it = 0; it < nks; ++it) {
        const int buf = it % 3;
        stage(ks0 + it + 2, (it + 2) % 3);   // unclamped tail over-fetch

        short* As = lds + buf * 12288;
        short* Bs = As + 4096;
        short8 a[4];
#pragma unroll
        for (int i = 0; i < 4; ++i)
            a[i] = *(const short8*)(As + ((wm * 4 + i) * 64 + l) * 8);

        if constexpr (HI) {
            short8 bf[8];
#pragma unroll
            for (int j = 0; j < 8; ++j)
                bf[j] = *(const short8*)(Bs + ((wn * 8 + j) * 64 + l) * 8);
            __builtin_amdgcn_s_setprio(1);
#pragma unroll
            for (int i = 0; i < 4; ++i)
#pragma unroll
                for (int h2 = 0; h2 < 2; ++h2)
#pragma unroll
                    for (int n = 0; n < 4; ++n)
                        acc[i][n] = __builtin_amdgcn_mfma_f32_16x16x32_bf16(
                            a[i], bf[h2 * 4 + n], acc[i][n], 0, 0, 0);
            __builtin_amdgcn_s_setprio(0);
        } else {
            short8 bf[4];
#pragma unroll
            for (int n = 0; n < 4; ++n)
                bf[n] = *(const short8*)(Bs + ((wn * 4 + n) * 64 + l) * 8);
            __builtin_amdgcn_s_setprio(1);
#pragma unroll
            for (int i = 0; i < 4; ++i)
#pragma unroll
                for (int n = 0; n < 4; ++n)
                    acc[i][n] = __builtin_amdgcn_mfma_f32_16x16x32_bf16(
                        a[i], bf[n], acc[i][n], 0, 0, 0);
            __builtin_amdgcn_s_setprio(0);
        }

        if constexpr (HI) { asm volatile("s_waitcnt vmcnt(6)" ::: "memory"); }
        else              { asm volatile("s_waitcnt vmcnt(4)" ::: "memory"); }
        __builtin_amdgcn_s_barrier();
        __builtin_amdgcn_sched_barrier(0);
    }

    // drain stray tail prefetches before LDS buffer reuse / endpgm
    asm volatile("s_waitcnt vmcnt(0)" ::: "memory");
    __builtin_amdgcn_s_barrier();
    __builtin_amdgcn_sched_barrier(0);
}

__global__ __launch_bounds__(256, 2) void gemm_step(
    const short* __restrict__ Ahi, const short* __restrict__ Alo,
    const short* __restrict__ Bx, const short* __restrict__ Bh,
    float* __restrict__ p, int t)
{
    __shared__ short lds[36864];   // 3 bufs x 24KB = 72 KB
    const int bb = (int)blockIdx.x;
    const int mb = bb >> 3, s = bb & 7;
    const int tid = (int)threadIdx.x;
    const int w = tid >> 6, l = tid & 63;
    const int wm = w >> 1, wn = w & 1;
    const int ping = t & 1;
    const int ks0 = (s < 2) ? s * 10 : 20 + (s - 2) * 9;
    const int nks = (s < 2) ? 10 : 9;
    const int boff = w * 512 + l * 8;            // lane-invariant B offset (shorts)
    const short* BhP = Bh + (size_t)ping * BHPING;

    float4v acc[4][4];
#pragma unroll
    for (int i = 0; i < 4; ++i)
#pragma unroll
        for (int n = 0; n < 4; ++n) acc[i][n] = (float4v){0.f, 0.f, 0.f, 0.f};

    const int stag = (bb & 1) ^ ((bb >> 8) & 1);
    if (stag == 0) {
        pass10<1>(Ahi + (size_t)mb * 74 * 4096, Bx, BhP, lds, acc,
                  ks0, nks, t, tid, wm, wn, l, boff);
        pass10<0>(Alo + (size_t)mb * 74 * 4096, Bx, BhP, lds, acc,
                  ks0, nks, t, tid, wm, wn, l, boff);
    } else {
        pass10<0>(Alo + (size_t)mb * 74 * 4096, Bx, BhP, lds, acc,
                  ks0, nks, t, tid, wm, wn, l, boff);
        pass10<1>(Ahi + (size_t)mb * 74 * 4096, Bx, BhP, lds, acc,
                  ks0, nks, t, tid, wm, wn, l, boff);
    }

    // epilogue: direct write of the full 3-term partial for this k-split
#pragma unroll
    for (int i = 0; i < 4; ++i)
#pragma unroll
        for (int n = 0; n < 4; ++n)
#pragma unroll
            for (int r = 0; r < 4; ++r) {
                int row = mb * 128 + wm * 64 + i * 16 + (l >> 4) * 4 + r;
                int col = wn * 64 + n * 16 + (l & 15);
                p[((size_t)s * 8192 + row) * 128 + col] = acc[i][n][r];
            }
}

// ================= new-path per-step update (round-11 rework) =================
// 256 blocks x 128 threads = 32768 threads; thread owns (dir, b, k-octet).
// p reads coalesced (lane = b); Bh writes become ONE aligned short8 per hi/lo
// (old kernel: 16 scattered 2B writes at 16B stride); out-writes 32B runs.
__global__ __launch_bounds__(128) void update3(
    const float* __restrict__ p,
    const float* __restrict__ b_ih, const float* __restrict__ b_hh,
    const int* __restrict__ lens,
    float* __restrict__ cbuf,       // [dir][2048][64] f32
    short* __restrict__ Bh,         // packed h hi/lo
    float* __restrict__ out, int t)
{
    const int tid = (int)(blockIdx.x * 128 + threadIdx.x);
    const int b    = tid & 63;
    const int kOct = (tid >> 6) & 255;
    const int dir  = tid >> 14;
    const int k0   = kOct * 8;

    float g[4][8];
#pragma unroll
    for (int gg = 0; gg < 4; ++gg)
#pragma unroll
        for (int j = 0; j < 8; ++j) g[gg][j] = 0.f;

    for (int s = 0; s < 8; ++s) {
#pragma unroll
        for (int gg = 0; gg < 4; ++gg) {
            const float* pr = p + ((size_t)s * 8192 + gg * 2048 + k0) * 128 + dir * 64 + b;
#pragma unroll
            for (int j = 0; j < 8; ++j)
                g[gg][j] += pr[(size_t)j * 128];
        }
    }
#pragma unroll
    for (int gg = 0; gg < 4; ++gg)
#pragma unroll
        for (int j = 0; j < 8; ++j) {
            int row = gg * 2048 + k0 + j;
            g[gg][j] += b_ih[row] + b_hh[row];
        }

    const int ksh = k0 >> 5;             // octet-aligned: constant over j
    const int kk8 = (k0 & 31) >> 3;
    const int ll  = kk8 * 16 + (b & 15);
    const int sub = b >> 4;
    const int pingW = (t + 1) & 1;
    const int len_b = lens[b];

    short8 vh, vl;
    float outv[8];
#pragma unroll
    for (int j = 0; j < 8; ++j) {
        const int k = k0 + j;
        const float iv = sigm(g[0][j]);
        const float fv = sigm(g[1][j]);
        const float gv = tanhf(g[2][j]);
        const float ov = sigm(g[3][j]);
        const size_t cidx = ((size_t)dir * 2048 + k) * 64 + b;
        const float c = fv * cbuf[cidx] + iv * gv;
        cbuf[cidx] = c;
        const float h = ov * tanhf(c);
        const unsigned hb = f2bf(h);
        vh[j] = (short)hb;
        vl[j] = (short)f2bf(h - bf2f(hb));
        outv[j] = h;
    }
    const size_t baseh = (size_t)pingW * BHPING + ((size_t)ksh * 16 + (dir * 2) * 4 + sub) * 512 + ll * 8;
    const size_t basel = (size_t)pingW * BHPING + ((size_t)ksh * 16 + (dir * 2 + 1) * 4 + sub) * 512 + ll * 8;
    *(short8*)(Bh + baseh) = vh;
    *(short8*)(Bh + basel) = vl;

    if (dir == 0) {
        if (t == len_b - 1) {
#pragma unroll
            for (int j = 0; j < 8; ++j) out[(size_t)b * 4096 + k0 + j] = outv[j];
        }
    } else {
        if (t == 127) {
#pragma unroll
            for (int j = 0; j < 8; ++j) out[(size_t)b * 4096 + 2048 + k0 + j] = outv[j];
        }
    }
}

// ======================================================================
// ================= round-2 fallback path (proven, ~102 MiB) ===========
// ======================================================================
#define R2K1    2368
#define R2EPAD  304
#define R2HOFF  304
#define R2HEND  2352
#define R2SEGSTEPS 74
#define R2REALSTEPS 222
#define R2SPLITSTEPS 56

__global__ void init_ws2(short* __restrict__ hb, float* __restrict__ cb,
                         short* __restrict__ zer) {
    const int nH = 2 * 2 * 2 * 64 * 2048;
    const int nC = 2 * 2048 * 64;
    int stride = gridDim.x * blockDim.x;
    int i = blockIdx.x * blockDim.x + threadIdx.x;
    for (int idx = i; idx < nH; idx += stride) hb[idx] = 0;
    for (int idx = i; idx < nC; idx += stride) cb[idx] = 0.f;
    for (int idx = i; idx < 128; idx += stride) zer[idx] = 0;
}

__global__ void conv_w(const float* __restrict__ Wih, const float* __restrict__ Whh,
                       short* __restrict__ whi, short* __restrict__ wlo) {
    int idx = blockIdx.x * blockDim.x + threadIdx.x;
    const int total = 8192 * R2K1;
    if (idx >= total) return;
    int j = idx / R2K1;
    int col = idx - j * R2K1;
    float w = 0.f;
    if (col < E_) w = Wih[(size_t)j * E_ + col];
    else if (col >= R2HOFF && col < R2HEND) w = Whh[(size_t)j * H_ + (col - R2HOFF)];
    unsigned hb = f2bf(w);
    whi[idx] = (short)hb;
    wlo[idx] = (short)f2bf(w - bf2f(hb));
}

__global__ void conv_x(const int* __restrict__ tokens, const float* __restrict__ embed,
                       short* __restrict__ xhi, short* __restrict__ xlo) {
    int idx = blockIdx.x * blockDim.x + threadIdx.x;
    const int total = T_ * B_ * R2EPAD;
    if (idx >= total) return;
    int t = idx / (B_ * R2EPAD);
    int r = idx - t * (B_ * R2EPAD);
    int bb = r / R2EPAD;
    int e = r - bb * R2EPAD;
    float v = 0.f;
    if (e < E_) {
        int tok = tokens[t * B_ + bb];
        v = embed[(size_t)tok * E_ + e];
    }
    unsigned hb = f2bf(v);
    xhi[idx] = (short)hb;
    xlo[idx] = (short)f2bf(v - bf2f(hb));
}

__global__ __launch_bounds__(512) void gemm_partial(
    const short* __restrict__ Whi, const short* __restrict__ Wlo,
    const short* __restrict__ xhi, const short* __restrict__ xlo,
    const short* __restrict__ hbuf,
    const short* __restrict__ zeros,
    float* __restrict__ pbuf, int t)
{
    __shared__ short As[2][8192];
    __shared__ short Bs[2][2048];

    const int bx  = blockIdx.x;
    const int s   = bx & 3;
    const int kt  = (bx >> 2) & 31;
    const int dir = bx >> 7;
    const int tid = threadIdx.x;
    const int w   = tid >> 6;
    const int l   = tid & 63;
    const int ping = t & 1;
    const int xt   = dir ? (T_ - 1 - t) : t;

    int jA[2], cA[2];
#pragma unroll
    for (int q = 0; q < 2; ++q) {
        int idx = (w * 2 + q) * 64 + l;
        cA[q] = idx >> 8;
        int row = idx & 255;
        jA[q] = (row >> 6) * 2048 + kt * 64 + (row & 63);
    }
    int cB = 0, bB = 0;
    if (w < 4) { int idx = w * 64 + l; cB = idx >> 6; bB = idx & 63; }

    const int lhi = l >> 4, llo = l & 15;
    const int rowbase = (w >> 1) * 64 + (w & 1) * 32;

    float4v acc[2][4];
#pragma unroll
    for (int a = 0; a < 2; ++a)
#pragma unroll
        for (int b = 0; b < 4; ++b) acc[a][b] = (float4v){0.f, 0.f, 0.f, 0.f};

    auto stage = [&](int g, int buf) {
        const bool dummy = (g >= R2REALSTEPS);
        const int seg = dummy ? 2 : g / R2SEGSTEPS;
        const int ss  = dummy ? 0 : g - seg * R2SEGSTEPS;
        const int kbase = ss * 32;
        const short* Wsel = (seg < 2) ? Whi : Wlo;
        const int hl = (seg == 1) ? 1 : 0;
        const short* xsel = (seg == 1) ? xlo : xhi;
        const short* hsel = hbuf + (((size_t)ping * 2 + hl) * 2 + dir) * (64 * 2048);
#pragma unroll
        for (int q = 0; q < 2; ++q) {
            const short* src = Wsel + (size_t)jA[q] * R2K1 + kbase + 8 * cA[q];
            gl_lds16(src, &As[buf][(w * 2 + q) * 64 * 8]);
        }
        if (w < 4) {
            int row8 = kbase + 8 * cB;
            const short* src;
            if (dummy || row8 >= R2HEND) src = zeros;
            else if (row8 < R2EPAD)      src = xsel + ((size_t)xt * 64 + bB) * R2EPAD + row8;
            else                         src = hsel + (size_t)bB * 2048 + (row8 - R2HOFF);
            gl_lds16(src, &Bs[buf][w * 64 * 8]);
        }
    };

    const int g0 = s * R2SPLITSTEPS;
    stage(g0, 0);

    for (int it = 0; it < R2SPLITSTEPS; ++it) {
        const int buf = it & 1;
        if (it + 1 < R2SPLITSTEPS) stage(g0 + it + 1, buf ^ 1);
        __syncthreads();
        short8 a0 = *(const short8*)&As[buf][(lhi * 256 + rowbase + llo) * 8];
        short8 a1 = *(const short8*)&As[buf][(lhi * 256 + rowbase + 16 + llo) * 8];
        short8 b0 = *(const short8*)&Bs[buf][(lhi * 64 + llo) * 8];
        short8 b1 = *(const short8*)&Bs[buf][(lhi * 64 + 16 + llo) * 8];
        short8 b2 = *(const short8*)&Bs[buf][(lhi * 64 + 32 + llo) * 8];
        short8 b3 = *(const short8*)&Bs[buf][(lhi * 64 + 48 + llo) * 8];
        acc[0][0] = __builtin_amdgcn_mfma_f32_16x16x32_bf16(a0, b0, acc[0][0], 0, 0, 0);
        acc[0][1] = __builtin_amdgcn_mfma_f32_16x16x32_bf16(a0, b1, acc[0][1], 0, 0, 0);
        acc[0][2] = __builtin_amdgcn_mfma_f32_16x16x32_bf16(a0, b2, acc[0][2], 0, 0, 0);
        acc[0][3] = __builtin_amdgcn_mfma_f32_16x16x32_bf16(a0, b3, acc[0][3], 0, 0, 0);
        acc[1][0] = __builtin_amdgcn_mfma_f32_16x16x32_bf16(a1, b0, acc[1][0], 0, 0, 0);
        acc[1][1] = __builtin_amdgcn_mfma_f32_16x16x32_bf16(a1, b1, acc[1][1], 0, 0, 0);
        acc[1][2] = __builtin_amdgcn_mfma_f32_16x16x32_bf16(a1, b2, acc[1][2], 0, 0, 0);
        acc[1][3] = __builtin_amdgcn_mfma_f32_16x16x32_bf16(a1, b3, acc[1][3], 0, 0, 0);
        __syncthreads();
    }

    float* pb = pbuf + (((size_t)(dir * 32 + kt) * 4 + s) * 256) * 64;
#pragma unroll
    for (int qm = 0; qm < 2; ++qm)
#pragma unroll
        for (int nb = 0; nb < 4; ++nb)
#pragma unroll
            for (int r = 0; r < 4; ++r) {
                int row = rowbase + qm * 16 + lhi * 4 + r;
                int col = nb * 16 + llo;
                pb[row * 64 + col] = acc[qm][nb][r];
            }
}

__global__ __launch_bounds__(256) void lstm_update(
    const float* __restrict__ pbuf,
    const float* __restrict__ b_ih, const float* __restrict__ b_hh,
    const int* __restrict__ lens,
    float* __restrict__ cbuf,
    short* __restrict__ hbuf,
    float* __restrict__ out, int t)
{
    const int bx = blockIdx.x;
    const int kt = bx & 31, dir = bx >> 5;
    const float* pb = pbuf + (size_t)(dir * 32 + kt) * 4 * 256 * 64;
    const int ping = (t + 1) & 1;

    for (int idx = threadIdx.x; idx < 4096; idx += 256) {
        const int q = idx >> 6, bb = idx & 63;
        const int k = kt * 64 + q;
        float gv[4];
#pragma unroll
        for (int gg = 0; gg < 4; ++gg) {
            const int r = gg * 64 + q;
            float v = 0.f;
#pragma unroll
            for (int s2 = 0; s2 < 4; ++s2) v += pb[(s2 * 256 + r) * 64 + bb];
            const int j = gg * 2048 + k;
            gv[gg] = v + b_ih[j] + b_hh[j];
        }
        const float iv = sigm(gv[0]);
        const float fv = sigm(gv[1]);
        const float g2 = tanhf(gv[2]);
        const float ov = sigm(gv[3]);
        const size_t cidx = ((size_t)dir * 2048 + k) * 64 + bb;
        const float c = fv * cbuf[cidx] + iv * g2;
        cbuf[cidx] = c;
        const float h = ov * tanhf(c);

        const unsigned hb = f2bf(h);
        const float hhi = bf2f(hb);
        const unsigned lb = f2bf(h - hhi);
        const size_t basehi = (((size_t)ping * 2 + 0) * 2 + dir) * (64 * 2048);
        const size_t baselo = (((size_t)ping * 2 + 1) * 2 + dir) * (64 * 2048);
        hbuf[basehi + (size_t)bb * 2048 + k] = (short)hb;
        hbuf[baselo + (size_t)bb * 2048 + k] = (short)lb;

        if (dir == 0) {
            if (t == lens[bb] - 1) out[(size_t)bb * (2 * H_) + k] = h;
        } else {
            if (t == T_ - 1) out[(size_t)bb * (2 * H_) + H_ + k] = h;
        }
    }
}

// ================= round-1 last-resort path =================
__global__ void init_state(float* __restrict__ hbuf, float* __restrict__ cbuf) {
    int n_h = 2 * 2 * H_ * B_;
    int n_c = 2 * H_ * B_;
    int stride = gridDim.x * blockDim.x;
    int i = blockIdx.x * blockDim.x + threadIdx.x;
    for (int idx = i; idx < n_h; idx += stride) hbuf[idx] = 0.f;
    for (int idx = i; idx < n_c; idx += stride) cbuf[idx] = 0.f;
}

__global__ void gather_x(const int* __restrict__ tokens, const float* __restrict__ embed,
                         float* __restrict__ x_t) {
    int idx = blockIdx.x * blockDim.x + threadIdx.x;
    int total = T_ * E_ * B_;
    if (idx >= total) return;
    int b = idx % B_;
    int r = idx / B_;
    int e = r % E_;
    int t = r / E_;
    int tok = tokens[t * B_ + b];
    x_t[idx] = embed[tok * E_ + e];
}

__global__ __launch_bounds__(256) void lstm_step(
    const float* __restrict__ x_t, const float* __restrict__ W_ih,
    const float* __restrict__ W_hh, const float* __restrict__ b_ih,
    const float* __restrict__ b_hh, const int* __restrict__ lens,
    const float* __restrict__ h_in, float* __restrict__ h_out,
    float* __restrict__ cbuf, float* __restrict__ out, int t)
{
    const int dir = blockIdx.x >> 8;
    const int kblk = blockIdx.x & 255;
    const int bpair = threadIdx.x & 31;
    const int kloc = threadIdx.x >> 5;
    const int k = kblk * 8 + kloc;
    const int b0 = bpair * 2;
    const int xt = dir ? (T_ - 1 - t) : t;
    const float* xrow = x_t + (size_t)xt * E_ * B_;
    const float* hrow = h_in + (size_t)dir * H_ * B_;
    float a0x = 0.f, a0y = 0.f, a1x = 0.f, a1y = 0.f;
    float a2x = 0.f, a2y = 0.f, a3x = 0.f, a3y = 0.f;
    {
        const float* w0 = W_ih + (size_t)(0 * H_ + k) * E_;
        const float* w1 = W_ih + (size_t)(1 * H_ + k) * E_;
        const float* w2 = W_ih + (size_t)(2 * H_ + k) * E_;
        const float* w3 = W_ih + (size_t)(3 * H_ + k) * E_;
#pragma unroll 4
        for (int kk = 0; kk < E_; ++kk) {
            float2 xv = *(const float2*)(xrow + kk * B_ + b0);
            float c0 = w0[kk], c1 = w1[kk], c2 = w2[kk], c3 = w3[kk];
            a0x += xv.x * c0; a0y += xv.y * c0;
            a1x += xv.x * c1; a1y += xv.y * c1;
            a2x += xv.x * c2; a2y += xv.y * c2;
            a3x += xv.x * c3; a3y += xv.y * c3;
        }
    }
    {
        const float* w0 = W_hh + (size_t)(0 * H_ + k) * H_;
        const float* w1 = W_hh + (size_t)(1 * H_ + k) * H_;
        const float* w2 = W_hh + (size_t)(2 * H_ + k) * H_;
        const float* w3 = W_hh + (size_t)(3 * H_ + k) * H_;
#pragma unroll 4
        for (int kk = 0; kk < H_; ++kk) {
            float2 hv = *(const float2*)(hrow + kk * B_ + b0);
            float c0 = w0[kk], c1 = w1[kk], c2 = w2[kk], c3 = w3[kk];
            a0x += hv.x * c0; a0y += hv.y * c0;
            a1x += hv.x * c1; a1y += hv.y * c1;
            a2x += hv.x * c2; a2y += hv.y * c2;
            a3x += hv.x * c3; a3y += hv.y * c3;
        }
    }
    const int j0 = 0 * H_ + k, j1 = 1 * H_ + k, j2 = 2 * H_ + k, j3 = 3 * H_ + k;
    const float bi = b_ih[j0] + b_hh[j0];
    const float bf = b_ih[j1] + b_hh[j1];
    const float bg = b_ih[j2] + b_hh[j2];
    const float bo = b_ih[j3] + b_hh[j3];
    float* cdir = cbuf + (size_t)dir * H_ * B_;
    float* hdir = h_out + (size_t)dir * H_ * B_;
#pragma unroll
    for (int s = 0; s < 2; ++s) {
        const int b = b0 + s;
        const float ai = (s == 0) ? a0x : a0y;
        const float af = (s == 0) ? a1x : a1y;
        const float ag = (s == 0) ? a2x : a2y;
        const float ao = (s == 0) ? a3x : a3y;
        const float iv = sigm(ai + bi);
        const float fv = sigm(af + bf);
        const float gv = tanhf(ag + bg);
        const float ov = sigm(ao + bo);
        const int sidx = k * B_ + b;
        const float c_old = cdir[sidx];
        const float c_new = fv * c_old + iv * gv;
        cdir[sidx] = c_new;
        const float h_new = ov * tanhf(c_new);
        hdir[sidx] = h_new;
        if (dir == 0) {
            if (t == lens[b] - 1) out[(size_t)b * (2 * H_) + k] = h_new;
        } else {
            if (t == T_ - 1) out[(size_t)b * (2 * H_) + H_ + k] = h_new;
        }
    }
}

// ================= launch =================
extern "C" void kernel_launch(void* const* d_in, const int* in_sizes, int n_in,
                              void* d_out, int out_size, void* d_ws, size_t ws_size,
                              hipStream_t stream) {
    const int*   tokens = (const int*)d_in[0];
    const int*   lens   = (const int*)d_in[1];
    const float* embed  = (const float*)d_in[2];
    const float* W_ih   = (const float*)d_in[3];
    const float* W_hh   = (const float*)d_in[4];
    const float* b_ih   = (const float*)d_in[5];
    const float* b_hh   = (const float*)d_in[6];
    float* out = (float*)d_out;

    // ---- new-path layout ----
    short* Ahi = (short*)d_ws;
    short* Alo = Ahi + APELEMS;
    short* BxP = Alo + APELEMS;
    short* BhP = BxP + BXELEMS;
    float* cb2n = (float*)(BhP + 2 * BHPING);
    float* pP   = cb2n + 262144;                 // [8][8192][128] f32
    const size_t req_new = (size_t)((char*)(pP + 8388608) - (char*)d_ws);

    // ---- r2 layout ----
    const size_t SZ_W  = (size_t)8192 * R2K1;
    const size_t SZ_X  = (size_t)T_ * B_ * R2EPAD;
    const size_t SZ_HB = (size_t)2 * 2 * 2 * 64 * 2048;
    const size_t SZ_CB = (size_t)2 * 2048 * 64;
    const size_t SZ_PB = (size_t)64 * 4 * 256 * 64;
    short* Whi2  = (short*)d_ws;
    short* Wlo2  = Whi2 + SZ_W;
    short* xhiB = Wlo2 + SZ_W;
    short* xloB = xhiB + SZ_X;
    short* hb2  = xloB + SZ_X;
    short* zer  = hb2 + SZ_HB;
    float* cb2  = (float*)(zer + 128);
    float* pbuf = cb2 + SZ_CB;
    const size_t req_r2 = (size_t)((char*)(pbuf + SZ_PB) - (char*)d_ws);

    if (ws_size >= req_new) {
        init2<<<512, 256, 0, stream>>>(BhP, cb2n);
        pack_w<<<(int)((APELEMS + 255) / 256), 256, 0, stream>>>(W_ih, W_hh, Ahi, Alo);
        pack_x<<<(int)((BXELEMS + 255) / 256), 256, 0, stream>>>(tokens, embed, BxP);
        for (int t = 0; t < T_; ++t) {
            gemm_step<<<512, 256, 0, stream>>>(Ahi, Alo, BxP, BhP, pP, t);
            update3<<<256, 128, 0, stream>>>(pP, b_ih, b_hh, lens, cb2n, BhP, out, t);
        }
    } else if (ws_size >= req_r2) {
        init_ws2<<<1024, 256, 0, stream>>>(hb2, cb2, zer);
        {
            int total = 8192 * R2K1;
            conv_w<<<(total + 255) / 256, 256, 0, stream>>>(W_ih, W_hh, Whi2, Wlo2);
        }
        {
            int total = T_ * B_ * R2EPAD;
            conv_x<<<(total + 255) / 256, 256, 0, stream>>>(tokens, embed, xhiB, xloB);
        }
        for (int t = 0; t < T_; ++t) {
            gemm_partial<<<256, 512, 0, stream>>>(Whi2, Wlo2, xhiB, xloB, hb2, zer, pbuf, t);
            lstm_update<<<64, 256, 0, stream>>>(pbuf, b_ih, b_hh, lens, cb2, hb2, out, t);
        }
    } else {
        float* ws   = (float*)d_ws;
        float* x_t  = ws;
        float* hbuf = x_t + (size_t)T_ * E_ * B_;
        float* cbuf = hbuf + (size_t)2 * 2 * H_ * B_;
        init_state<<<256, 256, 0, stream>>>(hbuf, cbuf);
        {
            int total = T_ * E_ * B_;
            gather_x<<<(total + 255) / 256, 256, 0, stream>>>(tokens, embed, x_t);
        }
        for (int t = 0; t < T_; ++t) {
            const float* h_in  = hbuf + (size_t)(t & 1) * 2 * H_ * B_;
            float*       h_out = hbuf + (size_t)((t + 1) & 1) * 2 * H_ * B_;
            lstm_step<<<512, 256, 0, stream>>>(x_t, W_ih, W_hh, b_ih, b_hh, lens,
                                               h_in, h_out, cbuf, out, t);
        }
    }
}

// Round 12
// 3727.542 us; speedup vs baseline: 1.1377x; 1.1377x over previous
//
#include <hip/hip_runtime.h>
#include <math.h>

#define T_ 128
#define B_ 64
#define E_ 300
#define H_ 2048

// ======== new-path geometry ========
// K layout: [0,300) x | [300,320) zero-pad | [320,2368) h   -> K1 = 2368 = 74 ksteps of 32
#define K1   2368
#define XKS  10      // x ksteps (320/32)
#define NKS  74      // total ksteps
#define APELEMS 19398656ull   // 8192 * 2368, per weight matrix (frag-major packed)
#define BXELEMS 5242880ull    // 128 t * 10 ks * 2 hl * 4 nf * 64 l * 8 j
#define BHPING  524288ull     // 64 ks * 16 nf * 64 l * 8 j   (shorts per ping)

typedef __attribute__((ext_vector_type(8))) short short8;
typedef __attribute__((ext_vector_type(4))) float float4v;

__device__ __forceinline__ unsigned f2bf(float f) {
    unsigned u = __float_as_uint(f);
    return (u + 0x7FFFu + ((u >> 16) & 1u)) >> 16;
}
__device__ __forceinline__ float bf2f(unsigned b) { return __uint_as_float(b << 16); }

__device__ __forceinline__ void gl_lds16(const void* g, void* l) {
    __builtin_amdgcn_global_load_lds(
        (const __attribute__((address_space(1))) unsigned int*)g,
        (__attribute__((address_space(3))) unsigned int*)l, 16, 0, 0);
}

__device__ __forceinline__ float sigm(float x) { return 1.f / (1.f + expf(-x)); }

// ================= new-path prologue =================

__global__ void init2(short* __restrict__ Bh, float* __restrict__ cb) {
    const int nB = 2 * (int)BHPING;     // shorts
    const int nC = 2 * 2048 * 64;       // floats
    int stride = gridDim.x * blockDim.x;
    int i = blockIdx.x * blockDim.x + threadIdx.x;
    for (int idx = i; idx < nB; idx += stride) Bh[idx] = 0;
    for (int idx = i; idx < nC; idx += stride) cb[idx] = 0.f;
}

// frag-major packed weights: [rb(64)][ks(74)][mf(8)][l(64)][j(8)]
// element = W[row = rb*128+mf*16+(l&15)][kr = ks*32+(l>>4)*8+j]
__global__ void pack_w(const float* __restrict__ Wih, const float* __restrict__ Whh,
                       short* __restrict__ Ahi, short* __restrict__ Alo) {
    long long idx = (long long)blockIdx.x * blockDim.x + threadIdx.x;
    if (idx >= (long long)APELEMS) return;
    int j  = (int)(idx & 7);
    int l  = (int)((idx >> 3) & 63);
    int mf = (int)((idx >> 9) & 7);
    int rest = (int)(idx >> 12);
    int ks = rest % 74;
    int rb = rest / 74;
    int row = rb * 128 + mf * 16 + (l & 15);
    int kr  = ks * 32 + (l >> 4) * 8 + j;
    float wv = 0.f;
    if (kr < 300)       wv = Wih[(size_t)row * 300 + kr];
    else if (kr >= 320) wv = Whh[(size_t)row * 2048 + (kr - 320)];
    unsigned hb = f2bf(wv);
    Ahi[idx] = (short)hb;
    Alo[idx] = (short)f2bf(wv - bf2f(hb));
}

// packed x: [t(128)][ks(10)][hl(2)][nf4(4)][l(64)][j(8)]
// col b = nf4*16+(l&15); kr = ks*32+(l>>4)*8+j
__global__ void pack_x(const int* __restrict__ tokens, const float* __restrict__ embed,
                       short* __restrict__ Bx) {
    long long idx = (long long)blockIdx.x * blockDim.x + threadIdx.x;
    if (idx >= (long long)BXELEMS) return;
    int j   = (int)(idx & 7);
    int l   = (int)((idx >> 3) & 63);
    int nf4 = (int)((idx >> 9) & 3);
    int hl  = (int)((idx >> 11) & 1);
    int rest = (int)(idx >> 12);
    int ks = rest % 10;
    int tt = rest / 10;
    int b  = nf4 * 16 + (l & 15);
    int kr = ks * 32 + (l >> 4) * 8 + j;
    float v = 0.f;
    if (kr < 300) {
        int tok = tokens[tt * 64 + b];
        v = embed[(size_t)tok * 300 + kr];
    }
    unsigned hb = f2bf(v);
    Bx[idx] = hl ? (short)f2bf(v - bf2f(hb)) : (short)hb;
}

// ================= new-path per-step GEMM (round-12: fused 3-term loop) =====
// 512 HOMOGENEOUS blocks = mb(64) x s(8); 256 threads (4 waves); 2 blocks/CU.
// Block M-tile 128 rows, k-split 9-10 ksteps. ONE loop per step: each kstep
// stages {Ahi 8KB, Alo 8KB, B=[vhi|vlo] 16KB} (32KB buffer) and computes all
// 48 MFMA/wave: Ahi x [vhi|vlo] merged (32) + Alo x vhi (16) into one acc.
// vs r10's two passes: B vhi staged ONCE (-20% staging), LDS reads -20%
// (16 b128 / 48 MFMA), iterations halved (10 vs 20), inter-pass drain gone.
// 2-buffer counted-vmcnt pipeline, distance 1 (8 loads/stage -> vmcnt(8));
// iteration ~2.5k cyc >> HBM latency so distance 1 suffices. Tail over-fetch
// UNCLAMPED (lands in adjacent ws buffers, valid, never consumed).
__global__ __launch_bounds__(256, 2) void gemm_step(
    const short* __restrict__ Ahi, const short* __restrict__ Alo,
    const short* __restrict__ Bx, const short* __restrict__ Bh,
    float* __restrict__ p, int t)
{
    __shared__ short lds[32768];   // 2 bufs x 32KB = 64 KB
    const int bb = (int)blockIdx.x;
    const int mb = bb >> 3, s = bb & 7;
    const int tid = (int)threadIdx.x;
    const int w = tid >> 6, l = tid & 63;
    const int wm = w >> 1, wn = w & 1;
    const int ping = t & 1;
    const int ks0 = (s < 2) ? s * 10 : 20 + (s - 2) * 9;
    const int nks = (s < 2) ? 10 : 9;
    const short* AhiB = Ahi + (size_t)mb * 74 * 4096;
    const short* AloB = Alo + (size_t)mb * 74 * 4096;
    const short* BhP  = Bh + (size_t)ping * BHPING;

    float4v acc[4][4];
#pragma unroll
    for (int i = 0; i < 4; ++i)
#pragma unroll
        for (int n = 0; n < 4; ++n) acc[i][n] = (float4v){0.f, 0.f, 0.f, 0.f};

    auto stage = [&](int ks, int buf) {
        short* As = lds + buf * 16384;
        short* Al = As + 4096;
        short* Bs = As + 8192;
        const short* aH = AhiB + (size_t)ks * 4096;
        const short* aL = AloB + (size_t)ks * 4096;
        gl_lds16(aH + tid * 8,        As + tid * 8);
        gl_lds16(aH + 2048 + tid * 8, As + 2048 + tid * 8);
        gl_lds16(aL + tid * 8,        Al + tid * 8);
        gl_lds16(aL + 2048 + tid * 8, Al + 2048 + tid * 8);
#pragma unroll
        for (int q = 0; q < 4; ++q) {
            const int dsel = q >> 1, hl = q & 1;   // compile-time per unrolled q
            const short* base;
            if (ks < XKS) {
                const int xt = dsel ? (127 - t) : t;
                base = Bx + (size_t)(((xt * 10 + ks) * 2 + hl) * 4) * 512;
            } else {
                base = BhP + (size_t)((ks - 10) * 16 + (dsel * 2 + hl) * 4) * 512;
            }
            gl_lds16(base + tid * 8, Bs + q * 2048 + tid * 8);
        }
    };

    stage(ks0, 0);
    for (int it = 0; it < nks; ++it) {
        stage(ks0 + it + 1, (it + 1) & 1);   // unclamped tail over-fetch
        asm volatile("s_waitcnt vmcnt(8)" ::: "memory");   // tile it landed
        __builtin_amdgcn_s_barrier();
        __builtin_amdgcn_sched_barrier(0);

        short* As = lds + (it & 1) * 16384;
        short* Al = As + 4096;
        short* Bs = As + 8192;
        short8 ah[4], al[4], bf[8];
#pragma unroll
        for (int i = 0; i < 4; ++i) {
            ah[i] = *(const short8*)(As + ((wm * 4 + i) * 64 + l) * 8);
            al[i] = *(const short8*)(Al + ((wm * 4 + i) * 64 + l) * 8);
        }
#pragma unroll
        for (int j = 0; j < 8; ++j)
            bf[j] = *(const short8*)(Bs + ((wn * 8 + j) * 64 + l) * 8);

        __builtin_amdgcn_s_setprio(1);
#pragma unroll
        for (int i = 0; i < 4; ++i)
#pragma unroll
            for (int h2 = 0; h2 < 2; ++h2)
#pragma unroll
                for (int n = 0; n < 4; ++n)
                    acc[i][n] = __builtin_amdgcn_mfma_f32_16x16x32_bf16(
                        ah[i], bf[h2 * 4 + n], acc[i][n], 0, 0, 0);
#pragma unroll
        for (int i = 0; i < 4; ++i)
#pragma unroll
            for (int n = 0; n < 4; ++n)
                acc[i][n] = __builtin_amdgcn_mfma_f32_16x16x32_bf16(
                    al[i], bf[n], acc[i][n], 0, 0, 0);   // bf[0..3] = vhi of dsel=wn
        __builtin_amdgcn_s_setprio(0);

        __builtin_amdgcn_s_barrier();     // all waves done with buf before overwrite
        __builtin_amdgcn_sched_barrier(0);
    }
    asm volatile("s_waitcnt vmcnt(0)" ::: "memory");   // drain tail over-fetch
    __builtin_amdgcn_s_barrier();
    __builtin_amdgcn_sched_barrier(0);

    // epilogue: direct write of the full 3-term partial for this k-split
#pragma unroll
    for (int i = 0; i < 4; ++i)
#pragma unroll
        for (int n = 0; n < 4; ++n)
#pragma unroll
            for (int r = 0; r < 4; ++r) {
                int row = mb * 128 + wm * 64 + i * 16 + (l >> 4) * 4 + r;
                int col = wn * 64 + n * 16 + (l & 15);
                p[((size_t)s * 8192 + row) * 128 + col] = acc[i][n][r];
            }
}

// ================= new-path per-step update (r10 proven version) =============
__global__ __launch_bounds__(256) void update2(
    const float* __restrict__ p,
    const float* __restrict__ b_ih, const float* __restrict__ b_hh,
    const int* __restrict__ lens,
    float* __restrict__ cbuf,       // [dir][2048][64] f32
    short* __restrict__ Bh,         // packed h hi/lo
    float* __restrict__ out, int t)
{
    int tid0 = blockIdx.x * 256 + threadIdx.x;
    for (int item = tid0; item < 262144; item += 65536) {
        int b = item & 63, k = (item >> 6) & 2047, dir = item >> 17;
        float g[4];
#pragma unroll
        for (int gg = 0; gg < 4; ++gg) {
            int row = gg * 2048 + k;
            float v = 0.f;
#pragma unroll
            for (int s = 0; s < 8; ++s) v += p[((size_t)s * 8192 + row) * 128 + dir * 64 + b];
            g[gg] = v + b_ih[row] + b_hh[row];
        }
        float iv = sigm(g[0]);
        float fv = sigm(g[1]);
        float gv = tanhf(g[2]);
        float ov = sigm(g[3]);
        size_t cidx = ((size_t)dir * 2048 + k) * 64 + b;
        float c = fv * cbuf[cidx] + iv * gv;
        cbuf[cidx] = c;
        float h = ov * tanhf(c);

        int kk = k & 31, ksh = k >> 5;
        int jj = kk & 7, ll = (kk >> 3) * 16 + (b & 15), sub = b >> 4;
        int pingW = (t + 1) & 1;
        size_t baseh = (size_t)pingW * BHPING + ((size_t)ksh * 16 + (dir * 2) * 4 + sub) * 512 + ll * 8 + jj;
        size_t basel = (size_t)pingW * BHPING + ((size_t)ksh * 16 + (dir * 2 + 1) * 4 + sub) * 512 + ll * 8 + jj;
        unsigned hb = f2bf(h);
        Bh[baseh] = (short)hb;
        Bh[basel] = (short)f2bf(h - bf2f(hb));

        if (dir == 0) { if (t == lens[b] - 1) out[(size_t)b * 4096 + k] = h; }
        else          { if (t == 127)         out[(size_t)b * 4096 + 2048 + k] = h; }
    }
}

// ======================================================================
// ================= round-2 fallback path (proven, ~102 MiB) ===========
// ======================================================================
#define R2K1    2368
#define R2EPAD  304
#define R2HOFF  304
#define R2HEND  2352
#define R2SEGSTEPS 74
#define R2REALSTEPS 222
#define R2SPLITSTEPS 56

__global__ void init_ws2(short* __restrict__ hb, float* __restrict__ cb,
                         short* __restrict__ zer) {
    const int nH = 2 * 2 * 2 * 64 * 2048;
    const int nC = 2 * 2048 * 64;
    int stride = gridDim.x * blockDim.x;
    int i = blockIdx.x * blockDim.x + threadIdx.x;
    for (int idx = i; idx < nH; idx += stride) hb[idx] = 0;
    for (int idx = i; idx < nC; idx += stride) cb[idx] = 0.f;
    for (int idx = i; idx < 128; idx += stride) zer[idx] = 0;
}

__global__ void conv_w(const float* __restrict__ Wih, const float* __restrict__ Whh,
                       short* __restrict__ whi, short* __restrict__ wlo) {
    int idx = blockIdx.x * blockDim.x + threadIdx.x;
    const int total = 8192 * R2K1;
    if (idx >= total) return;
    int j = idx / R2K1;
    int col = idx - j * R2K1;
    float w = 0.f;
    if (col < E_) w = Wih[(size_t)j * E_ + col];
    else if (col >= R2HOFF && col < R2HEND) w = Whh[(size_t)j * H_ + (col - R2HOFF)];
    unsigned hb = f2bf(w);
    whi[idx] = (short)hb;
    wlo[idx] = (short)f2bf(w - bf2f(hb));
}

__global__ void conv_x(const int* __restrict__ tokens, const float* __restrict__ embed,
                       short* __restrict__ xhi, short* __restrict__ xlo) {
    int idx = blockIdx.x * blockDim.x + threadIdx.x;
    const int total = T_ * B_ * R2EPAD;
    if (idx >= total) return;
    int t = idx / (B_ * R2EPAD);
    int r = idx - t * (B_ * R2EPAD);
    int bb = r / R2EPAD;
    int e = r - bb * R2EPAD;
    float v = 0.f;
    if (e < E_) {
        int tok = tokens[t * B_ + bb];
        v = embed[(size_t)tok * E_ + e];
    }
    unsigned hb = f2bf(v);
    xhi[idx] = (short)hb;
    xlo[idx] = (short)f2bf(v - bf2f(hb));
}

__global__ __launch_bounds__(512) void gemm_partial(
    const short* __restrict__ Whi, const short* __restrict__ Wlo,
    const short* __restrict__ xhi, const short* __restrict__ xlo,
    const short* __restrict__ hbuf,
    const short* __restrict__ zeros,
    float* __restrict__ pbuf, int t)
{
    __shared__ short As[2][8192];
    __shared__ short Bs[2][2048];

    const int bx  = blockIdx.x;
    const int s   = bx & 3;
    const int kt  = (bx >> 2) & 31;
    const int dir = bx >> 7;
    const int tid = threadIdx.x;
    const int w   = tid >> 6;
    const int l   = tid & 63;
    const int ping = t & 1;
    const int xt   = dir ? (T_ - 1 - t) : t;

    int jA[2], cA[2];
#pragma unroll
    for (int q = 0; q < 2; ++q) {
        int idx = (w * 2 + q) * 64 + l;
        cA[q] = idx >> 8;
        int row = idx & 255;
        jA[q] = (row >> 6) * 2048 + kt * 64 + (row & 63);
    }
    int cB = 0, bB = 0;
    if (w < 4) { int idx = w * 64 + l; cB = idx >> 6; bB = idx & 63; }

    const int lhi = l >> 4, llo = l & 15;
    const int rowbase = (w >> 1) * 64 + (w & 1) * 32;

    float4v acc[2][4];
#pragma unroll
    for (int a = 0; a < 2; ++a)
#pragma unroll
        for (int b = 0; b < 4; ++b) acc[a][b] = (float4v){0.f, 0.f, 0.f, 0.f};

    auto stage = [&](int g, int buf) {
        const bool dummy = (g >= R2REALSTEPS);
        const int seg = dummy ? 2 : g / R2SEGSTEPS;
        const int ss  = dummy ? 0 : g - seg * R2SEGSTEPS;
        const int kbase = ss * 32;
        const short* Wsel = (seg < 2) ? Whi : Wlo;
        const int hl = (seg == 1) ? 1 : 0;
        const short* xsel = (seg == 1) ? xlo : xhi;
        const short* hsel = hbuf + (((size_t)ping * 2 + hl) * 2 + dir) * (64 * 2048);
#pragma unroll
        for (int q = 0; q < 2; ++q) {
            const short* src = Wsel + (size_t)jA[q] * R2K1 + kbase + 8 * cA[q];
            gl_lds16(src, &As[buf][(w * 2 + q) * 64 * 8]);
        }
        if (w < 4) {
            int row8 = kbase + 8 * cB;
            const short* src;
            if (dummy || row8 >= R2HEND) src = zeros;
            else if (row8 < R2EPAD)      src = xsel + ((size_t)xt * 64 + bB) * R2EPAD + row8;
            else                         src = hsel + (size_t)bB * 2048 + (row8 - R2HOFF);
            gl_lds16(src, &Bs[buf][w * 64 * 8]);
        }
    };

    const int g0 = s * R2SPLITSTEPS;
    stage(g0, 0);

    for (int it = 0; it < R2SPLITSTEPS; ++it) {
        const int buf = it & 1;
        if (it + 1 < R2SPLITSTEPS) stage(g0 + it + 1, buf ^ 1);
        __syncthreads();
        short8 a0 = *(const short8*)&As[buf][(lhi * 256 + rowbase + llo) * 8];
        short8 a1 = *(const short8*)&As[buf][(lhi * 256 + rowbase + 16 + llo) * 8];
        short8 b0 = *(const short8*)&Bs[buf][(lhi * 64 + llo) * 8];
        short8 b1 = *(const short8*)&Bs[buf][(lhi * 64 + 16 + llo) * 8];
        short8 b2 = *(const short8*)&Bs[buf][(lhi * 64 + 32 + llo) * 8];
        short8 b3 = *(const short8*)&Bs[buf][(lhi * 64 + 48 + llo) * 8];
        acc[0][0] = __builtin_amdgcn_mfma_f32_16x16x32_bf16(a0, b0, acc[0][0], 0, 0, 0);
        acc[0][1] = __builtin_amdgcn_mfma_f32_16x16x32_bf16(a0, b1, acc[0][1], 0, 0, 0);
        acc[0][2] = __builtin_amdgcn_mfma_f32_16x16x32_bf16(a0, b2, acc[0][2], 0, 0, 0);
        acc[0][3] = __builtin_amdgcn_mfma_f32_16x16x32_bf16(a0, b3, acc[0][3], 0, 0, 0);
        acc[1][0] = __builtin_amdgcn_mfma_f32_16x16x32_bf16(a1, b0, acc[1][0], 0, 0, 0);
        acc[1][1] = __builtin_amdgcn_mfma_f32_16x16x32_bf16(a1, b1, acc[1][1], 0, 0, 0);
        acc[1][2] = __builtin_amdgcn_mfma_f32_16x16x32_bf16(a1, b2, acc[1][2], 0, 0, 0);
        acc[1][3] = __builtin_amdgcn_mfma_f32_16x16x32_bf16(a1, b3, acc[1][3], 0, 0, 0);
        __syncthreads();
    }

    float* pb = pbuf + (((size_t)(dir * 32 + kt) * 4 + s) * 256) * 64;
#pragma unroll
    for (int qm = 0; qm < 2; ++qm)
#pragma unroll
        for (int nb = 0; nb < 4; ++nb)
#pragma unroll
            for (int r = 0; r < 4; ++r) {
                int row = rowbase + qm * 16 + lhi * 4 + r;
                int col = nb * 16 + llo;
                pb[row * 64 + col] = acc[qm][nb][r];
            }
}

__global__ __launch_bounds__(256) void lstm_update(
    const float* __restrict__ pbuf,
    const float* __restrict__ b_ih, const float* __restrict__ b_hh,
    const int* __restrict__ lens,
    float* __restrict__ cbuf,
    short* __restrict__ hbuf,
    float* __restrict__ out, int t)
{
    const int bx = blockIdx.x;
    const int kt = bx & 31, dir = bx >> 5;
    const float* pb = pbuf + (size_t)(dir * 32 + kt) * 4 * 256 * 64;
    const int ping = (t + 1) & 1;

    for (int idx = threadIdx.x; idx < 4096; idx += 256) {
        const int q = idx >> 6, bb = idx & 63;
        const int k = kt * 64 + q;
        float gv[4];
#pragma unroll
        for (int gg = 0; gg < 4; ++gg) {
            const int r = gg * 64 + q;
            float v = 0.f;
#pragma unroll
            for (int s2 = 0; s2 < 4; ++s2) v += pb[(s2 * 256 + r) * 64 + bb];
            const int j = gg * 2048 + k;
            gv[gg] = v + b_ih[j] + b_hh[j];
        }
        const float iv = sigm(gv[0]);
        const float fv = sigm(gv[1]);
        const float g2 = tanhf(gv[2]);
        const float ov = sigm(gv[3]);
        const size_t cidx = ((size_t)dir * 2048 + k) * 64 + bb;
        const float c = fv * cbuf[cidx] + iv * g2;
        cbuf[cidx] = c;
        const float h = ov * tanhf(c);

        const unsigned hb = f2bf(h);
        const float hhi = bf2f(hb);
        const unsigned lb = f2bf(h - hhi);
        const size_t basehi = (((size_t)ping * 2 + 0) * 2 + dir) * (64 * 2048);
        const size_t baselo = (((size_t)ping * 2 + 1) * 2 + dir) * (64 * 2048);
        hbuf[basehi + (size_t)bb * 2048 + k] = (short)hb;
        hbuf[baselo + (size_t)bb * 2048 + k] = (short)lb;

        if (dir == 0) {
            if (t == lens[bb] - 1) out[(size_t)bb * (2 * H_) + k] = h;
        } else {
            if (t == T_ - 1) out[(size_t)bb * (2 * H_) + H_ + k] = h;
        }
    }
}

// ================= round-1 last-resort path =================
__global__ void init_state(float* __restrict__ hbuf, float* __restrict__ cbuf) {
    int n_h = 2 * 2 * H_ * B_;
    int n_c = 2 * H_ * B_;
    int stride = gridDim.x * blockDim.x;
    int i = blockIdx.x * blockDim.x + threadIdx.x;
    for (int idx = i; idx < n_h; idx += stride) hbuf[idx] = 0.f;
    for (int idx = i; idx < n_c; idx += stride) cbuf[idx] = 0.f;
}

__global__ void gather_x(const int* __restrict__ tokens, const float* __restrict__ embed,
                         float* __restrict__ x_t) {
    int idx = blockIdx.x * blockDim.x + threadIdx.x;
    int total = T_ * E_ * B_;
    if (idx >= total) return;
    int b = idx % B_;
    int r = idx / B_;
    int e = r % E_;
    int t = r / E_;
    int tok = tokens[t * B_ + b];
    x_t[idx] = embed[tok * E_ + e];
}

__global__ __launch_bounds__(256) void lstm_step(
    const float* __restrict__ x_t, const float* __restrict__ W_ih,
    const float* __restrict__ W_hh, const float* __restrict__ b_ih,
    const float* __restrict__ b_hh, const int* __restrict__ lens,
    const float* __restrict__ h_in, float* __restrict__ h_out,
    float* __restrict__ cbuf, float* __restrict__ out, int t)
{
    const int dir = blockIdx.x >> 8;
    const int kblk = blockIdx.x & 255;
    const int bpair = threadIdx.x & 31;
    const int kloc = threadIdx.x >> 5;
    const int k = kblk * 8 + kloc;
    const int b0 = bpair * 2;
    const int xt = dir ? (T_ - 1 - t) : t;
    const float* xrow = x_t + (size_t)xt * E_ * B_;
    const float* hrow = h_in + (size_t)dir * H_ * B_;
    float a0x = 0.f, a0y = 0.f, a1x = 0.f, a1y = 0.f;
    float a2x = 0.f, a2y = 0.f, a3x = 0.f, a3y = 0.f;
    {
        const float* w0 = W_ih + (size_t)(0 * H_ + k) * E_;
        const float* w1 = W_ih + (size_t)(1 * H_ + k) * E_;
        const float* w2 = W_ih + (size_t)(2 * H_ + k) * E_;
        const float* w3 = W_ih + (size_t)(3 * H_ + k) * E_;
#pragma unroll 4
        for (int kk = 0; kk < E_; ++kk) {
            float2 xv = *(const float2*)(xrow + kk * B_ + b0);
            float c0 = w0[kk], c1 = w1[kk], c2 = w2[kk], c3 = w3[kk];
            a0x += xv.x * c0; a0y += xv.y * c0;
            a1x += xv.x * c1; a1y += xv.y * c1;
            a2x += xv.x * c2; a2y += xv.y * c2;
            a3x += xv.x * c3; a3y += xv.y * c3;
        }
    }
    {
        const float* w0 = W_hh + (size_t)(0 * H_ + k) * H_;
        const float* w1 = W_hh + (size_t)(1 * H_ + k) * H_;
        const float* w2 = W_hh + (size_t)(2 * H_ + k) * H_;
        const float* w3 = W_hh + (size_t)(3 * H_ + k) * H_;
#pragma unroll 4
        for (int kk = 0; kk < H_; ++kk) {
            float2 hv = *(const float2*)(hrow + kk * B_ + b0);
            float c0 = w0[kk], c1 = w1[kk], c2 = w2[kk], c3 = w3[kk];
            a0x += hv.x * c0; a0y += hv.y * c0;
            a1x += hv.x * c1; a1y += hv.y * c1;
            a2x += hv.x * c2; a2y += hv.y * c2;
            a3x += hv.x * c3; a3y += hv.y * c3;
        }
    }
    const int j0 = 0 * H_ + k, j1 = 1 * H_ + k, j2 = 2 * H_ + k, j3 = 3 * H_ + k;
    const float bi = b_ih[j0] + b_hh[j0];
    const float bf = b_ih[j1] + b_hh[j1];
    const float bg = b_ih[j2] + b_hh[j2];
    const float bo = b_ih[j3] + b_hh[j3];
    float* cdir = cbuf + (size_t)dir * H_ * B_;
    float* hdir = h_out + (size_t)dir * H_ * B_;
#pragma unroll
    for (int s = 0; s < 2; ++s) {
        const int b = b0 + s;
        const float ai = (s == 0) ? a0x : a0y;
        const float af = (s == 0) ? a1x : a1y;
        const float ag = (s == 0) ? a2x : a2y;
        const float ao = (s == 0) ? a3x : a3y;
        const float iv = sigm(ai + bi);
        const float fv = sigm(af + bf);
        const float gv = tanhf(ag + bg);
        const float ov = sigm(ao + bo);
        const int sidx = k * B_ + b;
        const float c_old = cdir[sidx];
        const float c_new = fv * c_old + iv * gv;
        cdir[sidx] = c_new;
        const float h_new = ov * tanhf(c_new);
        hdir[sidx] = h_new;
        if (dir == 0) {
            if (t == lens[b] - 1) out[(size_t)b * (2 * H_) + k] = h_new;
        } else {
            if (t == T_ - 1) out[(size_t)b * (2 * H_) + H_ + k] = h_new;
        }
    }
}

// ================= launch =================
extern "C" void kernel_launch(void* const* d_in, const int* in_sizes, int n_in,
                              void* d_out, int out_size, void* d_ws, size_t ws_size,
                              hipStream_t stream) {
    const int*   tokens = (const int*)d_in[0];
    const int*   lens   = (const int*)d_in[1];
    const float* embed  = (const float*)d_in[2];
    const float* W_ih   = (const float*)d_in[3];
    const float* W_hh   = (const float*)d_in[4];
    const float* b_ih   = (const float*)d_in[5];
    const float* b_hh   = (const float*)d_in[6];
    float* out = (float*)d_out;

    // ---- new-path layout ----
    short* Ahi = (short*)d_ws;
    short* Alo = Ahi + APELEMS;
    short* BxP = Alo + APELEMS;
    short* BhP = BxP + BXELEMS;
    float* cb2n = (float*)(BhP + 2 * BHPING);
    float* pP   = cb2n + 262144;                 // [8][8192][128] f32
    const size_t req_new = (size_t)((char*)(pP + 8388608) - (char*)d_ws);

    // ---- r2 layout ----
    const size_t SZ_W  = (size_t)8192 * R2K1;
    const size_t SZ_X  = (size_t)T_ * B_ * R2EPAD;
    const size_t SZ_HB = (size_t)2 * 2 * 2 * 64 * 2048;
    const size_t SZ_CB = (size_t)2 * 2048 * 64;
    const size_t SZ_PB = (size_t)64 * 4 * 256 * 64;
    short* Whi2  = (short*)d_ws;
    short* Wlo2  = Whi2 + SZ_W;
    short* xhiB = Wlo2 + SZ_W;
    short* xloB = xhiB + SZ_X;
    short* hb2  = xloB + SZ_X;
    short* zer  = hb2 + SZ_HB;
    float* cb2  = (float*)(zer + 128);
    float* pbuf = cb2 + SZ_CB;
    const size_t req_r2 = (size_t)((char*)(pbuf + SZ_PB) - (char*)d_ws);

    if (ws_size >= req_new) {
        init2<<<512, 256, 0, stream>>>(BhP, cb2n);
        pack_w<<<(int)((APELEMS + 255) / 256), 256, 0, stream>>>(W_ih, W_hh, Ahi, Alo);
        pack_x<<<(int)((BXELEMS + 255) / 256), 256, 0, stream>>>(tokens, embed, BxP);
        for (int t = 0; t < T_; ++t) {
            gemm_step<<<512, 256, 0, stream>>>(Ahi, Alo, BxP, BhP, pP, t);
            update2<<<256, 256, 0, stream>>>(pP, b_ih, b_hh, lens, cb2n, BhP, out, t);
        }
    } else if (ws_size >= req_r2) {
        init_ws2<<<1024, 256, 0, stream>>>(hb2, cb2, zer);
        {
            int total = 8192 * R2K1;
            conv_w<<<(total + 255) / 256, 256, 0, stream>>>(W_ih, W_hh, Whi2, Wlo2);
        }
        {
            int total = T_ * B_ * R2EPAD;
            conv_x<<<(total + 255) / 256, 256, 0, stream>>>(tokens, embed, xhiB, xloB);
        }
        for (int t = 0; t < T_; ++t) {
            gemm_partial<<<256, 512, 0, stream>>>(Whi2, Wlo2, xhiB, xloB, hb2, zer, pbuf, t);
            lstm_update<<<64, 256, 0, stream>>>(pbuf, b_ih, b_hh, lens, cb2, hb2, out, t);
        }
    } else {
        float* ws   = (float*)d_ws;
        float* x_t  = ws;
        float* hbuf = x_t + (size_t)T_ * E_ * B_;
        float* cbuf = hbuf + (size_t)2 * 2 * H_ * B_;
        init_state<<<256, 256, 0, stream>>>(hbuf, cbuf);
        {
            int total = T_ * E_ * B_;
            gather_x<<<(total + 255) / 256, 256, 0, stream>>>(tokens, embed, x_t);
        }
        for (int t = 0; t < T_; ++t) {
            const float* h_in  = hbuf + (size_t)(t & 1) * 2 * H_ * B_;
            float*       h_out = hbuf + (size_t)((t + 1) & 1) * 2 * H_ * B_;
            lstm_step<<<512, 256, 0, stream>>>(x_t, W_ih, W_hh, b_ih, b_hh, lens,
                                               h_in, h_out, cbuf, out, t);
        }
    }
}

// Round 13
// 3649.483 us; speedup vs baseline: 1.1621x; 1.0214x over previous
//
#include <hip/hip_runtime.h>
#include <math.h>

#define T_ 128
#define B_ 64
#define E_ 300
#define H_ 2048

// ======== new-path geometry ========
// K layout: [0,300) x | [300,320) zero-pad | [320,2368) h   -> K1 = 2368 = 74 ksteps of 32
#define K1   2368
#define XKS  10      // x ksteps (320/32)
#define NKS  74      // total ksteps
#define APELEMS 19398656ull   // 8192 * 2368, per weight matrix (frag-major packed)
#define BXELEMS 5242880ull    // 128 t * 10 ks * 2 hl * 4 nf * 64 l * 8 j
#define BHPING  524288ull     // 64 ks * 16 nf * 64 l * 8 j   (shorts per ping)

typedef __attribute__((ext_vector_type(8))) short short8;
typedef __attribute__((ext_vector_type(4))) float float4v;

__device__ __forceinline__ unsigned f2bf(float f) {
    unsigned u = __float_as_uint(f);
    return (u + 0x7FFFu + ((u >> 16) & 1u)) >> 16;
}
__device__ __forceinline__ float bf2f(unsigned b) { return __uint_as_float(b << 16); }

__device__ __forceinline__ void gl_lds16(const void* g, void* l) {
    __builtin_amdgcn_global_load_lds(
        (const __attribute__((address_space(1))) unsigned int*)g,
        (__attribute__((address_space(3))) unsigned int*)l, 16, 0, 0);
}

__device__ __forceinline__ float sigm(float x) { return 1.f / (1.f + expf(-x)); }

// ================= new-path prologue =================

__global__ void init2(short* __restrict__ Bh, float* __restrict__ cb) {
    const int nB = 2 * (int)BHPING;     // shorts
    const int nC = 2 * 2048 * 64;       // floats
    int stride = gridDim.x * blockDim.x;
    int i = blockIdx.x * blockDim.x + threadIdx.x;
    for (int idx = i; idx < nB; idx += stride) Bh[idx] = 0;
    for (int idx = i; idx < nC; idx += stride) cb[idx] = 0.f;
}

// frag-major packed weights: [rb(64)][ks(74)][mf(8)][l(64)][j(8)]
// element = W[row = rb*128+mf*16+(l&15)][kr = ks*32+(l>>4)*8+j]
__global__ void pack_w(const float* __restrict__ Wih, const float* __restrict__ Whh,
                       short* __restrict__ Ahi, short* __restrict__ Alo) {
    long long idx = (long long)blockIdx.x * blockDim.x + threadIdx.x;
    if (idx >= (long long)APELEMS) return;
    int j  = (int)(idx & 7);
    int l  = (int)((idx >> 3) & 63);
    int mf = (int)((idx >> 9) & 7);
    int rest = (int)(idx >> 12);
    int ks = rest % 74;
    int rb = rest / 74;
    int row = rb * 128 + mf * 16 + (l & 15);
    int kr  = ks * 32 + (l >> 4) * 8 + j;
    float wv = 0.f;
    if (kr < 300)       wv = Wih[(size_t)row * 300 + kr];
    else if (kr >= 320) wv = Whh[(size_t)row * 2048 + (kr - 320)];
    unsigned hb = f2bf(wv);
    Ahi[idx] = (short)hb;
    Alo[idx] = (short)f2bf(wv - bf2f(hb));
}

// packed x: [t(128)][ks(10)][hl(2)][nf4(4)][l(64)][j(8)]
// col b = nf4*16+(l&15); kr = ks*32+(l>>4)*8+j
__global__ void pack_x(const int* __restrict__ tokens, const float* __restrict__ embed,
                       short* __restrict__ Bx) {
    long long idx = (long long)blockIdx.x * blockDim.x + threadIdx.x;
    if (idx >= (long long)BXELEMS) return;
    int j   = (int)(idx & 7);
    int l   = (int)((idx >> 3) & 63);
    int nf4 = (int)((idx >> 9) & 3);
    int hl  = (int)((idx >> 11) & 1);
    int rest = (int)(idx >> 12);
    int ks = rest % 10;
    int tt = rest / 10;
    int b  = nf4 * 16 + (l & 15);
    int kr = ks * 32 + (l >> 4) * 8 + j;
    float v = 0.f;
    if (kr < 300) {
        int tok = tokens[tt * 64 + b];
        v = embed[(size_t)tok * 300 + kr];
    }
    unsigned hb = f2bf(v);
    Bx[idx] = hl ? (short)f2bf(v - bf2f(hb)) : (short)hb;
}

// ================= new-path per-step GEMM (round-13: 1 barrier/kstep) =======
// 512 HOMOGENEOUS blocks = mb(64) x s(8); 256 threads (4 waves); 2 blocks/CU.
// Fused 3-term loop (r12): each kstep stages {Ahi 8KB, Alo 8KB, B 16KB} and
// computes 48 MFMA/wave into one acc. Round-13 change: SINGLE barrier per
// kstep. Iteration = {vmcnt(0); barrier} -> ds_read frags -> stage(it+1) ->
// MFMA. Safety: buf (it+1)&1 was last READ at iter it-1; those ds_reads
// complete before that iter's MFMAs issue (in-order + compiler lgkmcnt), which
// precede the iter-it barrier -> no wave can stage over unread data. The
// stage's VMEM latency hides under the 48-MFMA cluster (~2300 cyc >> HBM).
// Tail over-fetch UNCLAMPED (lands in adjacent ws buffers, never consumed).
__global__ __launch_bounds__(256, 2) void gemm_step(
    const short* __restrict__ Ahi, const short* __restrict__ Alo,
    const short* __restrict__ Bx, const short* __restrict__ Bh,
    float* __restrict__ p, int t)
{
    __shared__ short lds[32768];   // 2 bufs x 32KB = 64 KB
    const int bb = (int)blockIdx.x;
    const int mb = bb >> 3, s = bb & 7;
    const int tid = (int)threadIdx.x;
    const int w = tid >> 6, l = tid & 63;
    const int wm = w >> 1, wn = w & 1;
    const int ping = t & 1;
    const int ks0 = (s < 2) ? s * 10 : 20 + (s - 2) * 9;
    const int nks = (s < 2) ? 10 : 9;
    const short* AhiB = Ahi + (size_t)mb * 74 * 4096;
    const short* AloB = Alo + (size_t)mb * 74 * 4096;
    const short* BhP  = Bh + (size_t)ping * BHPING;

    float4v acc[4][4];
#pragma unroll
    for (int i = 0; i < 4; ++i)
#pragma unroll
        for (int n = 0; n < 4; ++n) acc[i][n] = (float4v){0.f, 0.f, 0.f, 0.f};

    auto stage = [&](int ks, int buf) {
        short* As = lds + buf * 16384;
        short* Al = As + 4096;
        short* Bs = As + 8192;
        const short* aH = AhiB + (size_t)ks * 4096;
        const short* aL = AloB + (size_t)ks * 4096;
        gl_lds16(aH + tid * 8,        As + tid * 8);
        gl_lds16(aH + 2048 + tid * 8, As + 2048 + tid * 8);
        gl_lds16(aL + tid * 8,        Al + tid * 8);
        gl_lds16(aL + 2048 + tid * 8, Al + 2048 + tid * 8);
#pragma unroll
        for (int q = 0; q < 4; ++q) {
            const int dsel = q >> 1, hl = q & 1;   // compile-time per unrolled q
            const short* base;
            if (ks < XKS) {
                const int xt = dsel ? (127 - t) : t;
                base = Bx + (size_t)(((xt * 10 + ks) * 2 + hl) * 4) * 512;
            } else {
                base = BhP + (size_t)((ks - 10) * 16 + (dsel * 2 + hl) * 4) * 512;
            }
            gl_lds16(base + tid * 8, Bs + q * 2048 + tid * 8);
        }
    };

    stage(ks0, 0);
    for (int it = 0; it < nks; ++it) {
        // single sync point: stage(it) landed (vmcnt) on every wave (barrier);
        // also gates reuse of buf (it+1)&1 (read last at iter it-1).
        asm volatile("s_waitcnt vmcnt(0)" ::: "memory");
        __builtin_amdgcn_s_barrier();
        __builtin_amdgcn_sched_barrier(0);

        short* As = lds + (it & 1) * 16384;
        short* Al = As + 4096;
        short* Bs = As + 8192;
        short8 ah[4], al[4], bf[8];
#pragma unroll
        for (int i = 0; i < 4; ++i) {
            ah[i] = *(const short8*)(As + ((wm * 4 + i) * 64 + l) * 8);
            al[i] = *(const short8*)(Al + ((wm * 4 + i) * 64 + l) * 8);
        }
#pragma unroll
        for (int j = 0; j < 8; ++j)
            bf[j] = *(const short8*)(Bs + ((wn * 8 + j) * 64 + l) * 8);

        stage(ks0 + it + 1, (it + 1) & 1);   // next tile; latency hides under MFMA

        __builtin_amdgcn_s_setprio(1);
#pragma unroll
        for (int i = 0; i < 4; ++i)
#pragma unroll
            for (int h2 = 0; h2 < 2; ++h2)
#pragma unroll
                for (int n = 0; n < 4; ++n)
                    acc[i][n] = __builtin_amdgcn_mfma_f32_16x16x32_bf16(
                        ah[i], bf[h2 * 4 + n], acc[i][n], 0, 0, 0);
#pragma unroll
        for (int i = 0; i < 4; ++i)
#pragma unroll
            for (int n = 0; n < 4; ++n)
                acc[i][n] = __builtin_amdgcn_mfma_f32_16x16x32_bf16(
                    al[i], bf[n], acc[i][n], 0, 0, 0);   // bf[0..3] = vhi of dsel=wn
        __builtin_amdgcn_s_setprio(0);
    }
    asm volatile("s_waitcnt vmcnt(0)" ::: "memory");   // drain tail over-fetch
    __builtin_amdgcn_s_barrier();
    __builtin_amdgcn_sched_barrier(0);

    // epilogue: direct write of the full 3-term partial for this k-split
#pragma unroll
    for (int i = 0; i < 4; ++i)
#pragma unroll
        for (int n = 0; n < 4; ++n)
#pragma unroll
            for (int r = 0; r < 4; ++r) {
                int row = mb * 128 + wm * 64 + i * 16 + (l >> 4) * 4 + r;
                int col = wn * 64 + n * 16 + (l & 15);
                p[((size_t)s * 8192 + row) * 128 + col] = acc[i][n][r];
            }
}

// ================= new-path per-step update (r10 proven version) =============
__global__ __launch_bounds__(256) void update2(
    const float* __restrict__ p,
    const float* __restrict__ b_ih, const float* __restrict__ b_hh,
    const int* __restrict__ lens,
    float* __restrict__ cbuf,       // [dir][2048][64] f32
    short* __restrict__ Bh,         // packed h hi/lo
    float* __restrict__ out, int t)
{
    int tid0 = blockIdx.x * 256 + threadIdx.x;
    for (int item = tid0; item < 262144; item += 65536) {
        int b = item & 63, k = (item >> 6) & 2047, dir = item >> 17;
        float g[4];
#pragma unroll
        for (int gg = 0; gg < 4; ++gg) {
            int row = gg * 2048 + k;
            float v = 0.f;
#pragma unroll
            for (int s = 0; s < 8; ++s) v += p[((size_t)s * 8192 + row) * 128 + dir * 64 + b];
            g[gg] = v + b_ih[row] + b_hh[row];
        }
        float iv = sigm(g[0]);
        float fv = sigm(g[1]);
        float gv = tanhf(g[2]);
        float ov = sigm(g[3]);
        size_t cidx = ((size_t)dir * 2048 + k) * 64 + b;
        float c = fv * cbuf[cidx] + iv * gv;
        cbuf[cidx] = c;
        float h = ov * tanhf(c);

        int kk = k & 31, ksh = k >> 5;
        int jj = kk & 7, ll = (kk >> 3) * 16 + (b & 15), sub = b >> 4;
        int pingW = (t + 1) & 1;
        size_t baseh = (size_t)pingW * BHPING + ((size_t)ksh * 16 + (dir * 2) * 4 + sub) * 512 + ll * 8 + jj;
        size_t basel = (size_t)pingW * BHPING + ((size_t)ksh * 16 + (dir * 2 + 1) * 4 + sub) * 512 + ll * 8 + jj;
        unsigned hb = f2bf(h);
        Bh[baseh] = (short)hb;
        Bh[basel] = (short)f2bf(h - bf2f(hb));

        if (dir == 0) { if (t == lens[b] - 1) out[(size_t)b * 4096 + k] = h; }
        else          { if (t == 127)         out[(size_t)b * 4096 + 2048 + k] = h; }
    }
}

// ======================================================================
// ================= round-2 fallback path (proven, ~102 MiB) ===========
// ======================================================================
#define R2K1    2368
#define R2EPAD  304
#define R2HOFF  304
#define R2HEND  2352
#define R2SEGSTEPS 74
#define R2REALSTEPS 222
#define R2SPLITSTEPS 56

__global__ void init_ws2(short* __restrict__ hb, float* __restrict__ cb,
                         short* __restrict__ zer) {
    const int nH = 2 * 2 * 2 * 64 * 2048;
    const int nC = 2 * 2048 * 64;
    int stride = gridDim.x * blockDim.x;
    int i = blockIdx.x * blockDim.x + threadIdx.x;
    for (int idx = i; idx < nH; idx += stride) hb[idx] = 0;
    for (int idx = i; idx < nC; idx += stride) cb[idx] = 0.f;
    for (int idx = i; idx < 128; idx += stride) zer[idx] = 0;
}

__global__ void conv_w(const float* __restrict__ Wih, const float* __restrict__ Whh,
                       short* __restrict__ whi, short* __restrict__ wlo) {
    int idx = blockIdx.x * blockDim.x + threadIdx.x;
    const int total = 8192 * R2K1;
    if (idx >= total) return;
    int j = idx / R2K1;
    int col = idx - j * R2K1;
    float w = 0.f;
    if (col < E_) w = Wih[(size_t)j * E_ + col];
    else if (col >= R2HOFF && col < R2HEND) w = Whh[(size_t)j * H_ + (col - R2HOFF)];
    unsigned hb = f2bf(w);
    whi[idx] = (short)hb;
    wlo[idx] = (short)f2bf(w - bf2f(hb));
}

__global__ void conv_x(const int* __restrict__ tokens, const float* __restrict__ embed,
                       short* __restrict__ xhi, short* __restrict__ xlo) {
    int idx = blockIdx.x * blockDim.x + threadIdx.x;
    const int total = T_ * B_ * R2EPAD;
    if (idx >= total) return;
    int t = idx / (B_ * R2EPAD);
    int r = idx - t * (B_ * R2EPAD);
    int bb = r / R2EPAD;
    int e = r - bb * R2EPAD;
    float v = 0.f;
    if (e < E_) {
        int tok = tokens[t * B_ + bb];
        v = embed[(size_t)tok * E_ + e];
    }
    unsigned hb = f2bf(v);
    xhi[idx] = (short)hb;
    xlo[idx] = (short)f2bf(v - bf2f(hb));
}

__global__ __launch_bounds__(512) void gemm_partial(
    const short* __restrict__ Whi, const short* __restrict__ Wlo,
    const short* __restrict__ xhi, const short* __restrict__ xlo,
    const short* __restrict__ hbuf,
    const short* __restrict__ zeros,
    float* __restrict__ pbuf, int t)
{
    __shared__ short As[2][8192];
    __shared__ short Bs[2][2048];

    const int bx  = blockIdx.x;
    const int s   = bx & 3;
    const int kt  = (bx >> 2) & 31;
    const int dir = bx >> 7;
    const int tid = threadIdx.x;
    const int w   = tid >> 6;
    const int l   = tid & 63;
    const int ping = t & 1;
    const int xt   = dir ? (T_ - 1 - t) : t;

    int jA[2], cA[2];
#pragma unroll
    for (int q = 0; q < 2; ++q) {
        int idx = (w * 2 + q) * 64 + l;
        cA[q] = idx >> 8;
        int row = idx & 255;
        jA[q] = (row >> 6) * 2048 + kt * 64 + (row & 63);
    }
    int cB = 0, bB = 0;
    if (w < 4) { int idx = w * 64 + l; cB = idx >> 6; bB = idx & 63; }

    const int lhi = l >> 4, llo = l & 15;
    const int rowbase = (w >> 1) * 64 + (w & 1) * 32;

    float4v acc[2][4];
#pragma unroll
    for (int a = 0; a < 2; ++a)
#pragma unroll
        for (int b = 0; b < 4; ++b) acc[a][b] = (float4v){0.f, 0.f, 0.f, 0.f};

    auto stage = [&](int g, int buf) {
        const bool dummy = (g >= R2REALSTEPS);
        const int seg = dummy ? 2 : g / R2SEGSTEPS;
        const int ss  = dummy ? 0 : g - seg * R2SEGSTEPS;
        const int kbase = ss * 32;
        const short* Wsel = (seg < 2) ? Whi : Wlo;
        const int hl = (seg == 1) ? 1 : 0;
        const short* xsel = (seg == 1) ? xlo : xhi;
        const short* hsel = hbuf + (((size_t)ping * 2 + hl) * 2 + dir) * (64 * 2048);
#pragma unroll
        for (int q = 0; q < 2; ++q) {
            const short* src = Wsel + (size_t)jA[q] * R2K1 + kbase + 8 * cA[q];
            gl_lds16(src, &As[buf][(w * 2 + q) * 64 * 8]);
        }
        if (w < 4) {
            int row8 = kbase + 8 * cB;
            const short* src;
            if (dummy || row8 >= R2HEND) src = zeros;
            else if (row8 < R2EPAD)      src = xsel + ((size_t)xt * 64 + bB) * R2EPAD + row8;
            else                         src = hsel + (size_t)bB * 2048 + (row8 - R2HOFF);
            gl_lds16(src, &Bs[buf][w * 64 * 8]);
        }
    };

    const int g0 = s * R2SPLITSTEPS;
    stage(g0, 0);

    for (int it = 0; it < R2SPLITSTEPS; ++it) {
        const int buf = it & 1;
        if (it + 1 < R2SPLITSTEPS) stage(g0 + it + 1, buf ^ 1);
        __syncthreads();
        short8 a0 = *(const short8*)&As[buf][(lhi * 256 + rowbase + llo) * 8];
        short8 a1 = *(const short8*)&As[buf][(lhi * 256 + rowbase + 16 + llo) * 8];
        short8 b0 = *(const short8*)&Bs[buf][(lhi * 64 + llo) * 8];
        short8 b1 = *(const short8*)&Bs[buf][(lhi * 64 + 16 + llo) * 8];
        short8 b2 = *(const short8*)&Bs[buf][(lhi * 64 + 32 + llo) * 8];
        short8 b3 = *(const short8*)&Bs[buf][(lhi * 64 + 48 + llo) * 8];
        acc[0][0] = __builtin_amdgcn_mfma_f32_16x16x32_bf16(a0, b0, acc[0][0], 0, 0, 0);
        acc[0][1] = __builtin_amdgcn_mfma_f32_16x16x32_bf16(a0, b1, acc[0][1], 0, 0, 0);
        acc[0][2] = __builtin_amdgcn_mfma_f32_16x16x32_bf16(a0, b2, acc[0][2], 0, 0, 0);
        acc[0][3] = __builtin_amdgcn_mfma_f32_16x16x32_bf16(a0, b3, acc[0][3], 0, 0, 0);
        acc[1][0] = __builtin_amdgcn_mfma_f32_16x16x32_bf16(a1, b0, acc[1][0], 0, 0, 0);
        acc[1][1] = __builtin_amdgcn_mfma_f32_16x16x32_bf16(a1, b1, acc[1][1], 0, 0, 0);
        acc[1][2] = __builtin_amdgcn_mfma_f32_16x16x32_bf16(a1, b2, acc[1][2], 0, 0, 0);
        acc[1][3] = __builtin_amdgcn_mfma_f32_16x16x32_bf16(a1, b3, acc[1][3], 0, 0, 0);
        __syncthreads();
    }

    float* pb = pbuf + (((size_t)(dir * 32 + kt) * 4 + s) * 256) * 64;
#pragma unroll
    for (int qm = 0; qm < 2; ++qm)
#pragma unroll
        for (int nb = 0; nb < 4; ++nb)
#pragma unroll
            for (int r = 0; r < 4; ++r) {
                int row = rowbase + qm * 16 + lhi * 4 + r;
                int col = nb * 16 + llo;
                pb[row * 64 + col] = acc[qm][nb][r];
            }
}

__global__ __launch_bounds__(256) void lstm_update(
    const float* __restrict__ pbuf,
    const float* __restrict__ b_ih, const float* __restrict__ b_hh,
    const int* __restrict__ lens,
    float* __restrict__ cbuf,
    short* __restrict__ hbuf,
    float* __restrict__ out, int t)
{
    const int bx = blockIdx.x;
    const int kt = bx & 31, dir = bx >> 5;
    const float* pb = pbuf + (size_t)(dir * 32 + kt) * 4 * 256 * 64;
    const int ping = (t + 1) & 1;

    for (int idx = threadIdx.x; idx < 4096; idx += 256) {
        const int q = idx >> 6, bb = idx & 63;
        const int k = kt * 64 + q;
        float gv[4];
#pragma unroll
        for (int gg = 0; gg < 4; ++gg) {
            const int r = gg * 64 + q;
            float v = 0.f;
#pragma unroll
            for (int s2 = 0; s2 < 4; ++s2) v += pb[(s2 * 256 + r) * 64 + bb];
            const int j = gg * 2048 + k;
            gv[gg] = v + b_ih[j] + b_hh[j];
        }
        const float iv = sigm(gv[0]);
        const float fv = sigm(gv[1]);
        const float g2 = tanhf(gv[2]);
        const float ov = sigm(gv[3]);
        const size_t cidx = ((size_t)dir * 2048 + k) * 64 + bb;
        const float c = fv * cbuf[cidx] + iv * g2;
        cbuf[cidx] = c;
        const float h = ov * tanhf(c);

        const unsigned hb = f2bf(h);
        const float hhi = bf2f(hb);
        const unsigned lb = f2bf(h - hhi);
        const size_t basehi = (((size_t)ping * 2 + 0) * 2 + dir) * (64 * 2048);
        const size_t baselo = (((size_t)ping * 2 + 1) * 2 + dir) * (64 * 2048);
        hbuf[basehi + (size_t)bb * 2048 + k] = (short)hb;
        hbuf[baselo + (size_t)bb * 2048 + k] = (short)lb;

        if (dir == 0) {
            if (t == lens[bb] - 1) out[(size_t)bb * (2 * H_) + k] = h;
        } else {
            if (t == T_ - 1) out[(size_t)bb * (2 * H_) + H_ + k] = h;
        }
    }
}

// ================= round-1 last-resort path =================
__global__ void init_state(float* __restrict__ hbuf, float* __restrict__ cbuf) {
    int n_h = 2 * 2 * H_ * B_;
    int n_c = 2 * H_ * B_;
    int stride = gridDim.x * blockDim.x;
    int i = blockIdx.x * blockDim.x + threadIdx.x;
    for (int idx = i; idx < n_h; idx += stride) hbuf[idx] = 0.f;
    for (int idx = i; idx < n_c; idx += stride) cbuf[idx] = 0.f;
}

__global__ void gather_x(const int* __restrict__ tokens, const float* __restrict__ embed,
                         float* __restrict__ x_t) {
    int idx = blockIdx.x * blockDim.x + threadIdx.x;
    int total = T_ * E_ * B_;
    if (idx >= total) return;
    int b = idx % B_;
    int r = idx / B_;
    int e = r % E_;
    int t = r / E_;
    int tok = tokens[t * B_ + b];
    x_t[idx] = embed[tok * E_ + e];
}

__global__ __launch_bounds__(256) void lstm_step(
    const float* __restrict__ x_t, const float* __restrict__ W_ih,
    const float* __restrict__ W_hh, const float* __restrict__ b_ih,
    const float* __restrict__ b_hh, const int* __restrict__ lens,
    const float* __restrict__ h_in, float* __restrict__ h_out,
    float* __restrict__ cbuf, float* __restrict__ out, int t)
{
    const int dir = blockIdx.x >> 8;
    const int kblk = blockIdx.x & 255;
    const int bpair = threadIdx.x & 31;
    const int kloc = threadIdx.x >> 5;
    const int k = kblk * 8 + kloc;
    const int b0 = bpair * 2;
    const int xt = dir ? (T_ - 1 - t) : t;
    const float* xrow = x_t + (size_t)xt * E_ * B_;
    const float* hrow = h_in + (size_t)dir * H_ * B_;
    float a0x = 0.f, a0y = 0.f, a1x = 0.f, a1y = 0.f;
    float a2x = 0.f, a2y = 0.f, a3x = 0.f, a3y = 0.f;
    {
        const float* w0 = W_ih + (size_t)(0 * H_ + k) * E_;
        const float* w1 = W_ih + (size_t)(1 * H_ + k) * E_;
        const float* w2 = W_ih + (size_t)(2 * H_ + k) * E_;
        const float* w3 = W_ih + (size_t)(3 * H_ + k) * E_;
#pragma unroll 4
        for (int kk = 0; kk < E_; ++kk) {
            float2 xv = *(const float2*)(xrow + kk * B_ + b0);
            float c0 = w0[kk], c1 = w1[kk], c2 = w2[kk], c3 = w3[kk];
            a0x += xv.x * c0; a0y += xv.y * c0;
            a1x += xv.x * c1; a1y += xv.y * c1;
            a2x += xv.x * c2; a2y += xv.y * c2;
            a3x += xv.x * c3; a3y += xv.y * c3;
        }
    }
    {
        const float* w0 = W_hh + (size_t)(0 * H_ + k) * H_;
        const float* w1 = W_hh + (size_t)(1 * H_ + k) * H_;
        const float* w2 = W_hh + (size_t)(2 * H_ + k) * H_;
        const float* w3 = W_hh + (size_t)(3 * H_ + k) * H_;
#pragma unroll 4
        for (int kk = 0; kk < H_; ++kk) {
            float2 hv = *(const float2*)(hrow + kk * B_ + b0);
            float c0 = w0[kk], c1 = w1[kk], c2 = w2[kk], c3 = w3[kk];
            a0x += hv.x * c0; a0y += hv.y * c0;
            a1x += hv.x * c1; a1y += hv.y * c1;
            a2x += hv.x * c2; a2y += hv.y * c2;
            a3x += hv.x * c3; a3y += hv.y * c3;
        }
    }
    const int j0 = 0 * H_ + k, j1 = 1 * H_ + k, j2 = 2 * H_ + k, j3 = 3 * H_ + k;
    const float bi = b_ih[j0] + b_hh[j0];
    const float bf = b_ih[j1] + b_hh[j1];
    const float bg = b_ih[j2] + b_hh[j2];
    const float bo = b_ih[j3] + b_hh[j3];
    float* cdir = cbuf + (size_t)dir * H_ * B_;
    float* hdir = h_out + (size_t)dir * H_ * B_;
#pragma unroll
    for (int s = 0; s < 2; ++s) {
        const int b = b0 + s;
        const float ai = (s == 0) ? a0x : a0y;
        const float af = (s == 0) ? a1x : a1y;
        const float ag = (s == 0) ? a2x : a2y;
        const float ao = (s == 0) ? a3x : a3y;
        const float iv = sigm(ai + bi);
        const float fv = sigm(af + bf);
        const float gv = tanhf(ag + bg);
        const float ov = sigm(ao + bo);
        const int sidx = k * B_ + b;
        const float c_old = cdir[sidx];
        const float c_new = fv * c_old + iv * gv;
        cdir[sidx] = c_new;
        const float h_new = ov * tanhf(c_new);
        hdir[sidx] = h_new;
        if (dir == 0) {
            if (t == lens[b] - 1) out[(size_t)b * (2 * H_) + k] = h_new;
        } else {
            if (t == T_ - 1) out[(size_t)b * (2 * H_) + H_ + k] = h_new;
        }
    }
}

// ================= launch =================
extern "C" void kernel_launch(void* const* d_in, const int* in_sizes, int n_in,
                              void* d_out, int out_size, void* d_ws, size_t ws_size,
                              hipStream_t stream) {
    const int*   tokens = (const int*)d_in[0];
    const int*   lens   = (const int*)d_in[1];
    const float* embed  = (const float*)d_in[2];
    const float* W_ih   = (const float*)d_in[3];
    const float* W_hh   = (const float*)d_in[4];
    const float* b_ih   = (const float*)d_in[5];
    const float* b_hh   = (const float*)d_in[6];
    float* out = (float*)d_out;

    // ---- new-path layout ----
    short* Ahi = (short*)d_ws;
    short* Alo = Ahi + APELEMS;
    short* BxP = Alo + APELEMS;
    short* BhP = BxP + BXELEMS;
    float* cb2n = (float*)(BhP + 2 * BHPING);
    float* pP   = cb2n + 262144;                 // [8][8192][128] f32
    const size_t req_new = (size_t)((char*)(pP + 8388608) - (char*)d_ws);

    // ---- r2 layout ----
    const size_t SZ_W  = (size_t)8192 * R2K1;
    const size_t SZ_X  = (size_t)T_ * B_ * R2EPAD;
    const size_t SZ_HB = (size_t)2 * 2 * 2 * 64 * 2048;
    const size_t SZ_CB = (size_t)2 * 2048 * 64;
    const size_t SZ_PB = (size_t)64 * 4 * 256 * 64;
    short* Whi2  = (short*)d_ws;
    short* Wlo2  = Whi2 + SZ_W;
    short* xhiB = Wlo2 + SZ_W;
    short* xloB = xhiB + SZ_X;
    short* hb2  = xloB + SZ_X;
    short* zer  = hb2 + SZ_HB;
    float* cb2  = (float*)(zer + 128);
    float* pbuf = cb2 + SZ_CB;
    const size_t req_r2 = (size_t)((char*)(pbuf + SZ_PB) - (char*)d_ws);

    if (ws_size >= req_new) {
        init2<<<512, 256, 0, stream>>>(BhP, cb2n);
        pack_w<<<(int)((APELEMS + 255) / 256), 256, 0, stream>>>(W_ih, W_hh, Ahi, Alo);
        pack_x<<<(int)((BXELEMS + 255) / 256), 256, 0, stream>>>(tokens, embed, BxP);
        for (int t = 0; t < T_; ++t) {
            gemm_step<<<512, 256, 0, stream>>>(Ahi, Alo, BxP, BhP, pP, t);
            update2<<<256, 256, 0, stream>>>(pP, b_ih, b_hh, lens, cb2n, BhP, out, t);
        }
    } else if (ws_size >= req_r2) {
        init_ws2<<<1024, 256, 0, stream>>>(hb2, cb2, zer);
        {
            int total = 8192 * R2K1;
            conv_w<<<(total + 255) / 256, 256, 0, stream>>>(W_ih, W_hh, Whi2, Wlo2);
        }
        {
            int total = T_ * B_ * R2EPAD;
            conv_x<<<(total + 255) / 256, 256, 0, stream>>>(tokens, embed, xhiB, xloB);
        }
        for (int t = 0; t < T_; ++t) {
            gemm_partial<<<256, 512, 0, stream>>>(Whi2, Wlo2, xhiB, xloB, hb2, zer, pbuf, t);
            lstm_update<<<64, 256, 0, stream>>>(pbuf, b_ih, b_hh, lens, cb2, hb2, out, t);
        }
    } else {
        float* ws   = (float*)d_ws;
        float* x_t  = ws;
        float* hbuf = x_t + (size_t)T_ * E_ * B_;
        float* cbuf = hbuf + (size_t)2 * 2 * H_ * B_;
        init_state<<<256, 256, 0, stream>>>(hbuf, cbuf);
        {
            int total = T_ * E_ * B_;
            gather_x<<<(total + 255) / 256, 256, 0, stream>>>(tokens, embed, x_t);
        }
        for (int t = 0; t < T_; ++t) {
            const float* h_in  = hbuf + (size_t)(t & 1) * 2 * H_ * B_;
            float*       h_out = hbuf + (size_t)((t + 1) & 1) * 2 * H_ * B_;
            lstm_step<<<512, 256, 0, stream>>>(x_t, W_ih, W_hh, b_ih, b_hh, lens,
                                               h_in, h_out, cbuf, out, t);
        }
    }
}